// Round 3
// baseline (216.637 us; speedup 1.0000x reference)
//
#include <hip/hip_runtime.h>

typedef __attribute__((ext_vector_type(8))) short short8;
typedef __attribute__((ext_vector_type(4))) float f32x4;
typedef __attribute__((ext_vector_type(4))) float float4v;
typedef __attribute__((ext_vector_type(4))) unsigned short ushort4v;
typedef unsigned short u16;

#define MFMA16(a, b, c) __builtin_amdgcn_mfma_f32_16x16x32_bf16((a), (b), (c), 0, 0, 0)

#define W_ 128
#define C_ 256
#define XB_LD 264   // xb [128][264] bf16 (pad 8)
#define VT_LD 136   // vT [256][136] bf16 (pad 8)
#define QK_LD 40    // q,k [128][40]
#define P_LD 136    // p [128][136]

__device__ __forceinline__ u16 f2bf(float f) {
    unsigned u = __builtin_bit_cast(unsigned, f);
    u += 0x7fffu + ((u >> 16) & 1u);   // RNE
    return (u16)(u >> 16);
}

// Pack weights into MFMA B-fragment order (bf16):
// pack[((kt*NCT + ct)*64 + lane)*8 + j] = w[kt*32 + (lane>>4)*8 + j][ct*16 + (lane&15)]
__global__ __launch_bounds__(256) void prep_pack(const float* __restrict__ wq,
                                                 const float* __restrict__ wk,
                                                 const float* __restrict__ wv,
                                                 u16* __restrict__ pack) {
    int t = blockIdx.x * 256 + threadIdx.x;   // 0 .. 81919
    int j = t & 7;
    int l = (t >> 3) & 63;
    int kr = ((l >> 4) << 3) + j;   // k offset within 32-chunk
    int lm = l & 15;
    if (t < 8192) {                 // wq: [256][32], NCT=2
        int g = t >> 9, ct = g & 1, kt = g >> 1;
        pack[t] = f2bf(wq[(kt * 32 + kr) * 32 + ct * 16 + lm]);
    } else if (t < 16384) {         // wk
        int u = t - 8192;
        int g = u >> 9, ct = g & 1, kt = g >> 1;
        pack[t] = f2bf(wk[(kt * 32 + kr) * 32 + ct * 16 + lm]);
    } else {                        // wv: [256][256], NCT=16
        int u = t - 16384;
        int g = u >> 9, ct = g & 15, kt = g >> 4;
        pack[t] = f2bf(wv[(kt * 32 + kr) * 256 + ct * 16 + lm]);
    }
}

__global__ __launch_bounds__(256) void attn_fused(
        const float* __restrict__ x,
        const u16* __restrict__ wq_p, const u16* __restrict__ wk_p,
        const u16* __restrict__ wv_p,
        const float* __restrict__ bq, const float* __restrict__ bk,
        const float* __restrict__ bv,
        float* __restrict__ out) {
    // LDS: 124928 bytes total
    __shared__ u16 uXV[34816];   // xb [128][264] (33792) then vT [256][136] (34816)
    __shared__ u16 uQ[128 * QK_LD];
    __shared__ u16 uK[128 * QK_LD];
    __shared__ u16 uP[128 * P_LD];

    const int bid = blockIdx.x;          // b*H + h
    const int tid = threadIdx.x;
    const int lane = tid & 63;
    const int wid = tid >> 6;            // 0..3
    const int lm = lane & 15;
    const int lq = lane >> 4;
    const int rowbase = wid * 32;        // this wave owns rows [rowbase, rowbase+32)
    const float* xs = x + (size_t)bid * (W_ * C_);

    // ---------------- Phase 0: x slice -> xb bf16 ----------------
    {
        int row0 = tid >> 6;             // wave id
        int col = (tid & 63) * 4;
#pragma unroll
        for (int i = 0; i < 32; ++i) {
            int row = row0 + 4 * i;
            float4v xv = *reinterpret_cast<const float4v*>(xs + row * C_ + col);
            ushort4v b4;
            b4[0] = f2bf(xv[0]); b4[1] = f2bf(xv[1]);
            b4[2] = f2bf(xv[2]); b4[3] = f2bf(xv[3]);
            *reinterpret_cast<ushort4v*>(&uXV[row * XB_LD + col]) = b4;
        }
    }
    __syncthreads();

    // ---------------- Phase 1: q = xb@wq + bq, k = xb@wk + bk ----------------
    {
        f32x4 qa[2][2] = {};   // [rt2][ct]
        f32x4 ka[2][2] = {};
#pragma unroll
        for (int kt = 0; kt < 8; ++kt) {
            short8 a0 = *reinterpret_cast<const short8*>(&uXV[(rowbase + lm) * XB_LD + kt * 32 + lq * 8]);
            short8 a1 = *reinterpret_cast<const short8*>(&uXV[(rowbase + 16 + lm) * XB_LD + kt * 32 + lq * 8]);
#pragma unroll
            for (int ct = 0; ct < 2; ++ct) {
                short8 bqf = *reinterpret_cast<const short8*>(wq_p + ((size_t)((kt * 2 + ct) * 64 + lane)) * 8);
                short8 bkf = *reinterpret_cast<const short8*>(wk_p + ((size_t)((kt * 2 + ct) * 64 + lane)) * 8);
                qa[0][ct] = MFMA16(a0, bqf, qa[0][ct]);
                qa[1][ct] = MFMA16(a1, bqf, qa[1][ct]);
                ka[0][ct] = MFMA16(a0, bkf, ka[0][ct]);
                ka[1][ct] = MFMA16(a1, bkf, ka[1][ct]);
            }
        }
#pragma unroll
        for (int rt2 = 0; rt2 < 2; ++rt2)
#pragma unroll
            for (int ct = 0; ct < 2; ++ct) {
                float bqv = bq[ct * 16 + lm];
                float bkv = bk[ct * 16 + lm];
#pragma unroll
                for (int r = 0; r < 4; ++r) {
                    int row = rowbase + rt2 * 16 + lq * 4 + r;
                    uQ[row * QK_LD + ct * 16 + lm] = f2bf(qa[rt2][ct][r] + bqv);
                    uK[row * QK_LD + ct * 16 + lm] = f2bf(ka[rt2][ct][r] + bkv);
                }
            }
    }
    __syncthreads();

    // ---------------- Phase 2+3: scores + softmax -> p bf16 ----------------
    {
        f32x4 s[2][8];
        short8 aq0 = *reinterpret_cast<const short8*>(&uQ[(rowbase + lm) * QK_LD + lq * 8]);
        short8 aq1 = *reinterpret_cast<const short8*>(&uQ[(rowbase + 16 + lm) * QK_LD + lq * 8]);
        f32x4 zero = {0.f, 0.f, 0.f, 0.f};
#pragma unroll
        for (int ct = 0; ct < 8; ++ct) {
            short8 bkf = *reinterpret_cast<const short8*>(&uK[(ct * 16 + lm) * QK_LD + lq * 8]);
            s[0][ct] = MFMA16(aq0, bkf, zero);
            s[1][ct] = MFMA16(aq1, bkf, zero);
        }
        // row softmax: row = rowbase + rt2*16 + lq*4 + r ; 16 lanes (fixed lq) x 8 regs
#pragma unroll
        for (int rt2 = 0; rt2 < 2; ++rt2) {
#pragma unroll
            for (int r = 0; r < 4; ++r) {
                float m = s[rt2][0][r];
#pragma unroll
                for (int ct = 1; ct < 8; ++ct) m = fmaxf(m, s[rt2][ct][r]);
                m = fmaxf(m, __shfl_xor(m, 1));
                m = fmaxf(m, __shfl_xor(m, 2));
                m = fmaxf(m, __shfl_xor(m, 4));
                m = fmaxf(m, __shfl_xor(m, 8));
                float e[8];
                float sum = 0.f;
#pragma unroll
                for (int ct = 0; ct < 8; ++ct) {
                    e[ct] = __expf(s[rt2][ct][r] - m);
                    sum += e[ct];
                }
                sum += __shfl_xor(sum, 1);
                sum += __shfl_xor(sum, 2);
                sum += __shfl_xor(sum, 4);
                sum += __shfl_xor(sum, 8);
                float inv = 1.0f / sum;
                int row = rowbase + rt2 * 16 + lq * 4 + r;
#pragma unroll
                for (int ct = 0; ct < 8; ++ct)
                    uP[row * P_LD + ct * 16 + lm] = f2bf(e[ct] * inv);
            }
        }
    }

    // ---------------- Phase 4: v = xb@wv + bv, write vT over xb ----------------
    {
        f32x4 vac[2][16] = {};
#pragma unroll
        for (int kt = 0; kt < 8; ++kt) {
            short8 a0 = *reinterpret_cast<const short8*>(&uXV[(rowbase + lm) * XB_LD + kt * 32 + lq * 8]);
            short8 a1 = *reinterpret_cast<const short8*>(&uXV[(rowbase + 16 + lm) * XB_LD + kt * 32 + lq * 8]);
#pragma unroll
            for (int ct = 0; ct < 16; ++ct) {
                short8 bvf = *reinterpret_cast<const short8*>(wv_p + ((size_t)((kt * 16 + ct) * 64 + lane)) * 8);
                vac[0][ct] = MFMA16(a0, bvf, vac[0][ct]);
                vac[1][ct] = MFMA16(a1, bvf, vac[1][ct]);
            }
        }
        __syncthreads();   // everyone done reading xb
#pragma unroll
        for (int rt2 = 0; rt2 < 2; ++rt2)
#pragma unroll
            for (int ct = 0; ct < 16; ++ct) {
                float bvv = bv[ct * 16 + lm];
                int wrow = rowbase + rt2 * 16 + lq * 4;
                ushort4v pk;
#pragma unroll
                for (int r = 0; r < 4; ++r) pk[r] = f2bf(vac[rt2][ct][r] + bvv);
                // vT[c][w], 4 consecutive w per lane -> packed 8B write
                *reinterpret_cast<ushort4v*>(&uXV[(ct * 16 + lm) * VT_LD + wrow]) = pk;
            }
    }
    __syncthreads();

    // ---------------- Phase 5: out = p @ v ----------------
    {
        f32x4 oac[2][16] = {};
#pragma unroll
        for (int kt = 0; kt < 4; ++kt) {
            short8 a0 = *reinterpret_cast<const short8*>(&uP[(rowbase + lm) * P_LD + kt * 32 + lq * 8]);
            short8 a1 = *reinterpret_cast<const short8*>(&uP[(rowbase + 16 + lm) * P_LD + kt * 32 + lq * 8]);
#pragma unroll
            for (int ct = 0; ct < 16; ++ct) {
                // B[k=w'][n=c] = v[w'][c] = vT[c][w'] -> contiguous 16B per lane
                short8 bvf = *reinterpret_cast<const short8*>(&uXV[(ct * 16 + lm) * VT_LD + kt * 32 + lq * 8]);
                oac[0][ct] = MFMA16(a0, bvf, oac[0][ct]);
                oac[1][ct] = MFMA16(a1, bvf, oac[1][ct]);
            }
        }
        float* os = out + (size_t)bid * (W_ * C_);
#pragma unroll
        for (int rt2 = 0; rt2 < 2; ++rt2)
#pragma unroll
            for (int ct = 0; ct < 16; ++ct)
#pragma unroll
                for (int r = 0; r < 4; ++r)
                    os[(rowbase + rt2 * 16 + lq * 4 + r) * C_ + ct * 16 + lm] = oac[rt2][ct][r];
    }
}

extern "C" void kernel_launch(void* const* d_in, const int* in_sizes, int n_in,
                              void* d_out, int out_size, void* d_ws, size_t ws_size,
                              hipStream_t stream) {
    const float* x  = (const float*)d_in[0];
    const float* wq = (const float*)d_in[1];
    const float* bq = (const float*)d_in[2];
    const float* wk = (const float*)d_in[3];
    const float* bk = (const float*)d_in[4];
    const float* wv = (const float*)d_in[5];
    const float* bv = (const float*)d_in[6];
    float* out = (float*)d_out;
    u16* pack = (u16*)d_ws;   // wq_p: 8192, wk_p: 8192, wv_p: 65536 u16 (160 KB total)

    prep_pack<<<320, 256, 0, stream>>>(wq, wk, wv, pack);
    attn_fused<<<2048, 256, 0, stream>>>(x, pack, pack + 8192, pack + 16384,
                                         bq, bk, bv, out);
}

// Round 4
// 216.199 us; speedup vs baseline: 1.0020x; 1.0020x over previous
//
#include <hip/hip_runtime.h>

typedef __attribute__((ext_vector_type(8))) short short8;
typedef __attribute__((ext_vector_type(4))) float f32x4;
typedef __attribute__((ext_vector_type(4))) float float4v;
typedef __attribute__((ext_vector_type(4))) unsigned short ushort4v;
typedef unsigned short u16;

#define MFMA16(a, b, c) __builtin_amdgcn_mfma_f32_16x16x32_bf16((a), (b), (c), 0, 0, 0)

#define W_ 128
#define C_ 256
#define XB_LD 264   // xb [128][264] bf16 (pad 8)
#define VT_LD 136   // vT [256][136] bf16 (pad 8)
#define QK_LD 40    // q,k [128][40]
#define P_LD 136    // p [128][136]

__device__ __forceinline__ u16 f2bf(float f) {
    unsigned u = __builtin_bit_cast(unsigned, f);
    u += 0x7fffu + ((u >> 16) & 1u);   // RNE
    return (u16)(u >> 16);
}

// Pack weights into MFMA B-fragment order (bf16):
// pack[((kt*NCT + ct)*64 + lane)*8 + j] = w[kt*32 + (lane>>4)*8 + j][ct*16 + (lane&15)]
__global__ __launch_bounds__(256) void prep_pack(const float* __restrict__ wq,
                                                 const float* __restrict__ wk,
                                                 const float* __restrict__ wv,
                                                 u16* __restrict__ pack) {
    int t = blockIdx.x * 256 + threadIdx.x;   // 0 .. 81919
    int j = t & 7;
    int l = (t >> 3) & 63;
    int kr = ((l >> 4) << 3) + j;   // k offset within 32-chunk
    int lm = l & 15;
    if (t < 8192) {                 // wq: [256][32], NCT=2
        int g = t >> 9, ct = g & 1, kt = g >> 1;
        pack[t] = f2bf(wq[(kt * 32 + kr) * 32 + ct * 16 + lm]);
    } else if (t < 16384) {         // wk
        int u = t - 8192;
        int g = u >> 9, ct = g & 1, kt = g >> 1;
        pack[t] = f2bf(wk[(kt * 32 + kr) * 32 + ct * 16 + lm]);
    } else {                        // wv: [256][256], NCT=16
        int u = t - 16384;
        int g = u >> 9, ct = g & 15, kt = g >> 4;
        pack[t] = f2bf(wv[(kt * 32 + kr) * 256 + ct * 16 + lm]);
    }
}

__global__ __launch_bounds__(256) void attn_fused(
        const float* __restrict__ x,
        const u16* __restrict__ wq_p, const u16* __restrict__ wk_p,
        const u16* __restrict__ wv_p,
        const float* __restrict__ bq, const float* __restrict__ bk,
        const float* __restrict__ bv,
        float* __restrict__ out) {
    // LDS: 124928 bytes total
    __shared__ u16 uXV[34816];   // xb [128][264] (33792) then vT [256][136] (34816)
    __shared__ u16 uQ[128 * QK_LD];
    __shared__ u16 uK[128 * QK_LD];
    __shared__ u16 uP[128 * P_LD];

    const int bid = blockIdx.x;          // b*H + h
    const int tid = threadIdx.x;
    const int lane = tid & 63;
    const int wid = tid >> 6;            // 0..3
    const int lm = lane & 15;
    const int lq = lane >> 4;
    const int rowbase = wid * 32;        // this wave owns rows [rowbase, rowbase+32)
    const float* xs = x + (size_t)bid * (W_ * C_);

    // ---------------- Phase 0: x slice -> xb bf16 ----------------
    {
        int row0 = tid >> 6;             // wave id
        int col = (tid & 63) * 4;
#pragma unroll
        for (int i = 0; i < 32; ++i) {
            int row = row0 + 4 * i;
            float4v xv = *reinterpret_cast<const float4v*>(xs + row * C_ + col);
            ushort4v b4;
            b4[0] = f2bf(xv[0]); b4[1] = f2bf(xv[1]);
            b4[2] = f2bf(xv[2]); b4[3] = f2bf(xv[3]);
            *reinterpret_cast<ushort4v*>(&uXV[row * XB_LD + col]) = b4;
        }
    }
    __syncthreads();

    // ---------------- Phase 1: q = xb@wq + bq, k = xb@wk + bk ----------------
    {
        f32x4 qa[2][2] = {};   // [rt2][ct]
        f32x4 ka[2][2] = {};
#pragma unroll
        for (int kt = 0; kt < 8; ++kt) {
            short8 a0 = *reinterpret_cast<const short8*>(&uXV[(rowbase + lm) * XB_LD + kt * 32 + lq * 8]);
            short8 a1 = *reinterpret_cast<const short8*>(&uXV[(rowbase + 16 + lm) * XB_LD + kt * 32 + lq * 8]);
#pragma unroll
            for (int ct = 0; ct < 2; ++ct) {
                short8 bqf = *reinterpret_cast<const short8*>(wq_p + ((size_t)((kt * 2 + ct) * 64 + lane)) * 8);
                short8 bkf = *reinterpret_cast<const short8*>(wk_p + ((size_t)((kt * 2 + ct) * 64 + lane)) * 8);
                qa[0][ct] = MFMA16(a0, bqf, qa[0][ct]);
                qa[1][ct] = MFMA16(a1, bqf, qa[1][ct]);
                ka[0][ct] = MFMA16(a0, bkf, ka[0][ct]);
                ka[1][ct] = MFMA16(a1, bkf, ka[1][ct]);
            }
        }
#pragma unroll
        for (int rt2 = 0; rt2 < 2; ++rt2)
#pragma unroll
            for (int ct = 0; ct < 2; ++ct) {
                float bqv = bq[ct * 16 + lm];
                float bkv = bk[ct * 16 + lm];
#pragma unroll
                for (int r = 0; r < 4; ++r) {
                    int row = rowbase + rt2 * 16 + lq * 4 + r;
                    uQ[row * QK_LD + ct * 16 + lm] = f2bf(qa[rt2][ct][r] + bqv);
                    uK[row * QK_LD + ct * 16 + lm] = f2bf(ka[rt2][ct][r] + bkv);
                }
            }
    }
    __syncthreads();

    // ---------------- Phase 2+3: scores + softmax -> p bf16 ----------------
    {
        f32x4 s[2][8];
        short8 aq0 = *reinterpret_cast<const short8*>(&uQ[(rowbase + lm) * QK_LD + lq * 8]);
        short8 aq1 = *reinterpret_cast<const short8*>(&uQ[(rowbase + 16 + lm) * QK_LD + lq * 8]);
        f32x4 zero = {0.f, 0.f, 0.f, 0.f};
#pragma unroll
        for (int ct = 0; ct < 8; ++ct) {
            short8 bkf = *reinterpret_cast<const short8*>(&uK[(ct * 16 + lm) * QK_LD + lq * 8]);
            s[0][ct] = MFMA16(aq0, bkf, zero);
            s[1][ct] = MFMA16(aq1, bkf, zero);
        }
        // row softmax: row = rowbase + rt2*16 + lq*4 + r ; 16 lanes (fixed lq) x 8 regs
#pragma unroll
        for (int rt2 = 0; rt2 < 2; ++rt2) {
#pragma unroll
            for (int r = 0; r < 4; ++r) {
                float m = s[rt2][0][r];
#pragma unroll
                for (int ct = 1; ct < 8; ++ct) m = fmaxf(m, s[rt2][ct][r]);
                m = fmaxf(m, __shfl_xor(m, 1));
                m = fmaxf(m, __shfl_xor(m, 2));
                m = fmaxf(m, __shfl_xor(m, 4));
                m = fmaxf(m, __shfl_xor(m, 8));
                float e[8];
                float sum = 0.f;
#pragma unroll
                for (int ct = 0; ct < 8; ++ct) {
                    e[ct] = __expf(s[rt2][ct][r] - m);
                    sum += e[ct];
                }
                sum += __shfl_xor(sum, 1);
                sum += __shfl_xor(sum, 2);
                sum += __shfl_xor(sum, 4);
                sum += __shfl_xor(sum, 8);
                float inv = 1.0f / sum;
                int row = rowbase + rt2 * 16 + lq * 4 + r;
#pragma unroll
                for (int ct = 0; ct < 8; ++ct)
                    uP[row * P_LD + ct * 16 + lm] = f2bf(e[ct] * inv);
            }
        }
    }

    // ---------------- Phase 4: v = xb@wv + bv, write vT over xb ----------------
    {
        f32x4 vac[2][16] = {};
#pragma unroll
        for (int kt = 0; kt < 8; ++kt) {
            short8 a0 = *reinterpret_cast<const short8*>(&uXV[(rowbase + lm) * XB_LD + kt * 32 + lq * 8]);
            short8 a1 = *reinterpret_cast<const short8*>(&uXV[(rowbase + 16 + lm) * XB_LD + kt * 32 + lq * 8]);
#pragma unroll
            for (int ct = 0; ct < 16; ++ct) {
                short8 bvf = *reinterpret_cast<const short8*>(wv_p + ((size_t)((kt * 16 + ct) * 64 + lane)) * 8);
                vac[0][ct] = MFMA16(a0, bvf, vac[0][ct]);
                vac[1][ct] = MFMA16(a1, bvf, vac[1][ct]);
            }
        }
        __syncthreads();   // everyone done reading xb
#pragma unroll
        for (int rt2 = 0; rt2 < 2; ++rt2)
#pragma unroll
            for (int ct = 0; ct < 16; ++ct) {
                float bvv = bv[ct * 16 + lm];
                int wrow = rowbase + rt2 * 16 + lq * 4;
                ushort4v pk;
#pragma unroll
                for (int r = 0; r < 4; ++r) pk[r] = f2bf(vac[rt2][ct][r] + bvv);
                // vT[c][w], 4 consecutive w per lane -> packed 8B write
                *reinterpret_cast<ushort4v*>(&uXV[(ct * 16 + lm) * VT_LD + wrow]) = pk;
            }
    }
    __syncthreads();

    // ---------------- Phase 5: out = p @ v ----------------
    {
        f32x4 oac[2][16] = {};
#pragma unroll
        for (int kt = 0; kt < 4; ++kt) {
            short8 a0 = *reinterpret_cast<const short8*>(&uP[(rowbase + lm) * P_LD + kt * 32 + lq * 8]);
            short8 a1 = *reinterpret_cast<const short8*>(&uP[(rowbase + 16 + lm) * P_LD + kt * 32 + lq * 8]);
#pragma unroll
            for (int ct = 0; ct < 16; ++ct) {
                // B[k=w'][n=c] = v[w'][c] = vT[c][w'] -> contiguous 16B per lane
                short8 bvf = *reinterpret_cast<const short8*>(&uXV[(ct * 16 + lm) * VT_LD + kt * 32 + lq * 8]);
                oac[0][ct] = MFMA16(a0, bvf, oac[0][ct]);
                oac[1][ct] = MFMA16(a1, bvf, oac[1][ct]);
            }
        }
        float* os = out + (size_t)bid * (W_ * C_);
#pragma unroll
        for (int rt2 = 0; rt2 < 2; ++rt2)
#pragma unroll
            for (int ct = 0; ct < 16; ++ct)
#pragma unroll
                for (int r = 0; r < 4; ++r)
                    os[(rowbase + rt2 * 16 + lq * 4 + r) * C_ + ct * 16 + lm] = oac[rt2][ct][r];
    }
}

extern "C" void kernel_launch(void* const* d_in, const int* in_sizes, int n_in,
                              void* d_out, int out_size, void* d_ws, size_t ws_size,
                              hipStream_t stream) {
    const float* x  = (const float*)d_in[0];
    const float* wq = (const float*)d_in[1];
    const float* bq = (const float*)d_in[2];
    const float* wk = (const float*)d_in[3];
    const float* bk = (const float*)d_in[4];
    const float* wv = (const float*)d_in[5];
    const float* bv = (const float*)d_in[6];
    float* out = (float*)d_out;
    u16* pack = (u16*)d_ws;   // wq_p: 8192, wk_p: 8192, wv_p: 65536 u16 (160 KB total)

    prep_pack<<<320, 256, 0, stream>>>(wq, wk, wv, pack);
    attn_fused<<<2048, 256, 0, stream>>>(x, pack, pack + 8192, pack + 16384,
                                         bq, bk, bv, out);
}